// Round 10
// baseline (518.598 us; speedup 1.0000x reference)
//
#include <hip/hip_runtime.h>
#include <cstdint>
#include <cstddef>

// Problem constants
#define B_ROWS 16384
#define FEAT   2048
#define FIELD  32
#define KDIM   64
#define NCOLS  2048           // FIELD*KDIM (main quadratic columns)
#define NAUG   2176           // 2048 + 64 (vsum) + 1 (w) + 63 zero-pad

using half8   = __attribute__((ext_vector_type(8))) _Float16;
using half4   = __attribute__((ext_vector_type(4))) _Float16;
using floatx4 = __attribute__((ext_vector_type(4))) float;

// Async global->LDS, 16B per lane. LDS dest must be wave-uniform base + lane*16.
__device__ __forceinline__ void load_lds16(const void* g, void* l) {
  __builtin_amdgcn_global_load_lds((const __attribute__((address_space(1))) void*)g,
                                   (__attribute__((address_space(3))) void*)l, 16, 0, 0);
}

// --- prep A: v transpose + vsum + w/zero rows + arg zero (runs FIRST) ------
__global__ __launch_bounds__(256) void k_prep_v(const float* __restrict__ v,
                                                const float* __restrict__ w,
                                                _Float16* __restrict__ vt,
                                                float* __restrict__ arg) {
  const int bb = blockIdx.x;
  const int t = threadIdx.x;
  if (bb < 1024) {
    __shared__ _Float16 tile[64 * 68];
    const int f0 = (bb >> 5) * 64;
    const int n0 = (bb & 31) * 64;
#pragma unroll
    for (int j = 0; j < 4; ++j) {
      int c = j * 256 + t;
      int row = c >> 4;                           // f local
      int col = (c & 15) * 4;                     // n local
      float4 val = *(const float4*)(v + (size_t)(f0 + row) * NCOLS + n0 + col);
      tile[row * 68 + col + 0] = (_Float16)val.x;
      tile[row * 68 + col + 1] = (_Float16)val.y;
      tile[row * 68 + col + 2] = (_Float16)val.z;
      tile[row * 68 + col + 3] = (_Float16)val.w;
    }
    __syncthreads();
#pragma unroll
    for (int j = 0; j < 4; ++j) {
      int c = j * 256 + t;
      int nl = c >> 4;                            // n local (row of vt)
      int fl = (c & 15) * 4;                      // f local group of 4
      half4 h = { tile[(fl + 0) * 68 + nl], tile[(fl + 1) * 68 + nl],
                  tile[(fl + 2) * 68 + nl], tile[(fl + 3) * 68 + nl] };
      *(half4*)(vt + (size_t)(n0 + nl) * FEAT + f0 + fl) = h;
    }
  } else if (bb < 1536) {
    const int k = t & 63;
    const int f = (bb - 1024) * 4 + (t >> 6);
    float s = 0.f;
#pragma unroll
    for (int si = 0; si < FIELD; ++si) s += v[(size_t)f * NCOLS + si * KDIM + k];
    vt[(size_t)(NCOLS + k) * FEAT + f] = (_Float16)s;
  } else if (bb < 2048) {
    int idx = (bb - 1536) * 256 + t;              // 64*2048 elements
    int r = NCOLS + KDIM + (idx >> 11);           // 2112..2175
    int f = idx & 2047;
    vt[(size_t)r * FEAT + f] = (r == NCOLS + KDIM) ? (_Float16)w[f] : (_Float16)0.f;
  } else {
    arg[(bb - 2048) * 256 + t] = 0.f;
  }
}

// --- prep B: x fp32 -> xh fp16 FUSED with the aug thin-GEMM (R9-verified) --
__global__ __launch_bounds__(256) void k_prep_xa(const float* __restrict__ x,
                                                 const _Float16* __restrict__ vt,
                                                 _Float16* __restrict__ xh,
                                                 float* __restrict__ arg) {
  __shared__ __align__(16) _Float16 lds_a[32 * 64];
  __shared__ __align__(16) _Float16 lds_b[128 * 64];
  const int t = threadIdx.x;
  const int m0 = blockIdx.x * 32;
  const int lane = t & 63;
  const int wave = t >> 6;
  const int wm = (wave & 1) * 16;               // M offset (1 frag row)
  const int wn = (wave >> 1) * 64;              // N offset (4 frag cols)
  const int lr = lane & 15;
  const int lk = (lane >> 4) * 8;

  const int arow = t >> 3;
  const int akc  = t & 7;
  const float*    xsrc = x  + (size_t)(m0 + arow) * FEAT + akc * 8;
  _Float16*       xdst = xh + (size_t)(m0 + arow) * FEAT + akc * 8;
  _Float16*       adst = lds_a + arow * 64 + (akc ^ (arow & 7)) * 8;

  floatx4 acc[4] = {};

  for (int k0 = 0; k0 < FEAT; k0 += 64) {
    float4 va = *(const float4*)(xsrc + k0);
    float4 vb = *(const float4*)(xsrc + k0 + 4);
    half8 h = { (_Float16)va.x, (_Float16)va.y, (_Float16)va.z, (_Float16)va.w,
                (_Float16)vb.x, (_Float16)vb.y, (_Float16)vb.z, (_Float16)vb.w };
    *(half8*)(xdst + k0) = h;                   // xh for the main gemm
    *(half8*)adst = h;                          // swizzled LDS A-tile
#pragma unroll
    for (int i = 0; i < 4; ++i) {
      int c = i * 256 + t;                      // 0..1023
      int row = c >> 3;
      int g = (c & 7) ^ (row & 7);
      load_lds16(vt + (size_t)(NCOLS + row) * FEAT + k0 + g * 8, lds_b + c * 8);
    }
    __syncthreads();
#pragma unroll
    for (int ks = 0; ks < 64; ks += 32) {
      const int kc = (ks + lk) >> 3;
      const int ma = wm + lr;
      half8 af = *(const half8*)(lds_a + ma * 64 + (kc ^ (ma & 7)) * 8);
      half8 bf[4];
#pragma unroll
      for (int f = 0; f < 4; ++f) {
        int nb = wn + f * 16 + lr;
        bf[f] = *(const half8*)(lds_b + nb * 64 + (kc ^ (nb & 7)) * 8);
      }
#pragma unroll
      for (int fn = 0; fn < 4; ++fn)
        acc[fn] = __builtin_amdgcn_mfma_f32_16x16x32_f16(af, bf[fn],
                                                         acc[fn], 0, 0, 0);
    }
    __syncthreads();
  }

  const int cq = lane >> 4;
#pragma unroll
  for (int r = 0; r < 4; ++r) {
    float contrib = 0.f;
#pragma unroll
    for (int fn = 0; fn < 4; ++fn) {
      int col = wn + fn * 16 + lr;
      float vv = acc[fn][r];
      if (col < KDIM)            contrib += 0.5f * vv * vv;
      else if (col == KDIM)      contrib += vv;
    }
    contrib += __shfl_xor(contrib, 1);
    contrib += __shfl_xor(contrib, 2);
    contrib += __shfl_xor(contrib, 4);
    contrib += __shfl_xor(contrib, 8);
    if (lr == 0) atomicAdd(&arg[m0 + wm + cq * 4 + r], contrib);
  }
}

// --- main GEMM (cols 0..2047) + row-reduce epilogue ------------------------
// R10 = R5's reg-prefetch pipeline (VERIFIED correct: R5 passed) + R8's
// zero-tail grid (VERIFIED fast: 512 = 64m x 8n, 2 full rounds, 2-n-group
// XCD decode -> 2MB B L2-resident/XCD).  R5's 455us was the m-fast grid's
// L2 thrash (FETCH 600MB), not the schedule; R9's cycle model shows the
// R8 skeleton serializes 2304 cyc LDS reads + 2480 cyc MFMA per K-tile
// (= measured 2.125us). This pipeline overlaps them:
//   each phase: {read NEXT phase's frags; stage one granule; [SCHED0]
//                PRIO(1); MFMA on PREV phase's frags; PRIO(0); waits}
//   ONE barrier per phase; compiler's auto-lgkmcnt before MFMA is ~free
//   (operands issued a full phase earlier). Explicit LGKM0 at end-ph0 /
//   end-ph2 enforce the WAR invariant before segment restage (rule #18).
//   Counted vmcnt at phase ends (own-wave drain BEFORE shared barrier):
//   end-ph0 vmcnt(6)->kg1(t); end-ph2 vmcnt(6)->kg0(t+1); tails 4/0.
// Stage schedule per iter t: ph0: A kg1(t+1)->buf^1  ph1: B kg1(t+1)->buf^1
//                            ph2: A kg0(t+2)->buf    ph3: B kg0(t+2)->buf
// LDS: segA(buf,kg) = ((buf<<1)|kg)*8192 halves, segB = +32768. 128 KiB.
// All B rows < 2048 (n0 <= 1792, row <= 191) -> no clamp; all cols < 2048
// -> epilogue uniformly -0.5c^2.
#define NT 32

#define VMCNT(N) asm volatile("s_waitcnt vmcnt(" #N ")" ::: "memory")
#define LGKM0()  asm volatile("s_waitcnt lgkmcnt(0)" ::: "memory")
#define SCHED0() __builtin_amdgcn_sched_barrier(0)
#define BARRIER() __builtin_amdgcn_s_barrier()
#define PRIO(N) __builtin_amdgcn_s_setprio(N)

__global__ __launch_bounds__(512, 2) void k_gemm(const _Float16* __restrict__ xh,
                                                 const _Float16* __restrict__ vt,
                                                 float* __restrict__ arg) {
  __shared__ __align__(16) _Float16 lds[65536];   // 128 KiB
  const int tid  = threadIdx.x;
  const int lane = tid & 63;
  const int wave = tid >> 6;      // 0..7
  const int wm   = wave >> 2;     // 0..1 -> M offset wm*128
  const int wn   = wave & 3;      // 0..3 -> N offset wn*64
  const int lr   = lane & 15;     // frag row (A) / col (B)
  const int q    = lane >> 4;     // k-chunk within 32-k granule

  // R8 grid decode: XCD swizzle (512 = 8*64, bijective) + 2-n-group.
  const int bid = blockIdx.x;
  const int wg  = (bid & 7) * 64 + (bid >> 3);
  const int ng  = wg >> 7;
  const int rem = wg & 127;
  const int mi  = rem >> 1;
  const int nr  = rem & 1;
  const int m0  = mi * 256;
  const int n0  = (ng * 2 + nr) * 256;           // 0..1792

  // fragment LDS offsets (halves) within any granule segment.
  int offA[4], offB[4];
#pragma unroll
  for (int f = 0; f < 4; ++f) {
    int L = f * 16 + lr;
    int u = wm * 4 + q;
    offA[f] = L * 64 + ((u ^ (L & 7)) * 8);
  }
#pragma unroll
  for (int g = 0; g < 4; ++g) {
    int L = (wn & 1) * 64 + g * 16 + lr;
    int u = (wn >> 1) * 4 + q;
    offB[g] = L * 64 + ((u ^ (L & 7)) * 8);
  }

  // staging source decode: linear chunk tid -> (row, kc); dest+4096 -> row+64.
  const int L0   = tid >> 3;
  const int u0   = (tid & 7) ^ (L0 & 7);
  const int row0 = (u0 >> 2) * 128 + L0;
  const int kc0  = u0 & 3;
  const _Float16* pA0 = xh + (size_t)(m0 + row0) * FEAT + kc0 * 8;
  const _Float16* pA1 = pA0 + (size_t)64 * FEAT;
  const _Float16* pB0 = vt + (size_t)(n0 + row0) * FEAT + kc0 * 8;  // rows < 2048
  const _Float16* pB1 = pB0 + (size_t)64 * FEAT;

  auto stageA = [&](int koff, int seg) {
    load_lds16(pA0 + koff, lds + seg + tid * 8);
    load_lds16(pA1 + koff, lds + seg + 4096 + tid * 8);
  };
  auto stageB = [&](int koff, int seg) {
    load_lds16(pB0 + koff, lds + seg + tid * 8);
    load_lds16(pB1 + koff, lds + seg + 4096 + tid * 8);
  };

  floatx4 acc[8][4] = {};
  half8 afP[4], afQ[4], bf0[4], bf1[4];

  // prologue: kg0(0), kg1(0), kg0(1) in that exact issue order (12 loads).
  stageA(0, 0);       stageB(0, 32768);
  stageA(32, 8192);   stageB(32, 40960);
  stageA(64, 16384);  stageB(64, 49152);
  VMCNT(8);                      // own kg0(0) landed
  BARRIER();                     // -> everyone's kg0(0) landed
  SCHED0();
#pragma unroll
  for (int f = 0; f < 4; ++f) afP[f] = *(const half8*)(lds + offA[f]);
#pragma unroll
  for (int g = 0; g < 4; ++g) bf0[g] = *(const half8*)(lds + 32768 + offB[g]);

#pragma unroll 2
  for (int t = 0; t < NT; ++t) {
    const int sA0  = (t & 1) << 14;        // segA(buf, kg0)
    const int sA1  = sA0 + 8192;           // segA(buf, kg1)
    const int sB0  = 32768 + sA0;
    const int sB1  = sB0 + 8192;
    const int nsA0 = sA0 ^ 16384;          // segA(buf^1, kg0)
    const int nsA1 = nsA0 + 8192;
    const int nsB0 = 32768 + nsA0;
    const int nsB1 = nsB0 + 8192;

    // ---- ph0: MFMA kg0 x af-lo; prefetch afQ (kg0 hi); stage A kg1(t+1) ---
    BARRIER(); SCHED0();
#pragma unroll
    for (int f = 0; f < 4; ++f) afQ[f] = *(const half8*)(lds + sA0 + 4096 + offA[f]);
    if (t + 1 < NT) stageA((t + 1) * 64 + 32, nsA1);
    SCHED0(); PRIO(1);
#pragma unroll
    for (int f = 0; f < 4; ++f)
#pragma unroll
      for (int g = 0; g < 4; ++g)
        acc[f][g] = __builtin_amdgcn_mfma_f32_16x16x32_f16(afP[f], bf0[g],
                                                           acc[f][g], 0, 0, 0);
    PRIO(0); SCHED0();
    LGKM0();                               // own ph0 reads (sA0-hi) complete
    if (t < NT - 1) { VMCNT(6); } else { VMCNT(0); }   // kg1(t) landed (own)

    // ---- ph1: MFMA kg0 x af-hi; prefetch afP,bf1 (kg1); stage B kg1(t+1) --
    BARRIER(); SCHED0();
#pragma unroll
    for (int f = 0; f < 4; ++f) afP[f] = *(const half8*)(lds + sA1 + offA[f]);
#pragma unroll
    for (int g = 0; g < 4; ++g) bf1[g] = *(const half8*)(lds + sB1 + offB[g]);
    if (t + 1 < NT) stageB((t + 1) * 64 + 32, nsB1);
    SCHED0(); PRIO(1);
#pragma unroll
    for (int f = 0; f < 4; ++f)
#pragma unroll
      for (int g = 0; g < 4; ++g)
        acc[4 + f][g] = __builtin_amdgcn_mfma_f32_16x16x32_f16(afQ[f], bf0[g],
                                                               acc[4 + f][g], 0, 0, 0);
    PRIO(0); SCHED0();

    // ---- ph2: MFMA kg1 x af-lo; prefetch afQ (kg1 hi); stage A kg0(t+2) ---
    BARRIER(); SCHED0();
#pragma unroll
    for (int f = 0; f < 4; ++f) afQ[f] = *(const half8*)(lds + sA1 + 4096 + offA[f]);
    if (t + 2 < NT) stageA((t + 2) * 64, sA0);
    SCHED0(); PRIO(1);
#pragma unroll
    for (int f = 0; f < 4; ++f)
#pragma unroll
      for (int g = 0; g < 4; ++g)
        acc[f][g] = __builtin_amdgcn_mfma_f32_16x16x32_f16(afP[f], bf1[g],
                                                           acc[f][g], 0, 0, 0);
    PRIO(0); SCHED0();
    LGKM0();                               // own ph1+ph2 reads (sA1,sB1) complete
    if (t < NT - 2)       { VMCNT(6); }                 // kg0(t+1) landed (own)
    else if (t == NT - 2) { VMCNT(4); }

    // ---- ph3: MFMA kg1 x af-hi; prefetch afP,bf0 (next kg0); stage B ------
    BARRIER(); SCHED0();
    if (t + 1 < NT) {
#pragma unroll
      for (int f = 0; f < 4; ++f) afP[f] = *(const half8*)(lds + nsA0 + offA[f]);
#pragma unroll
      for (int g = 0; g < 4; ++g) bf0[g] = *(const half8*)(lds + nsB0 + offB[g]);
    }
    if (t + 2 < NT) stageB((t + 2) * 64, sB0);
    SCHED0(); PRIO(1);
#pragma unroll
    for (int f = 0; f < 4; ++f)
#pragma unroll
      for (int g = 0; g < 4; ++g)
        acc[4 + f][g] = __builtin_amdgcn_mfma_f32_16x16x32_f16(afQ[f], bf1[g],
                                                               acc[4 + f][g], 0, 0, 0);
    PRIO(0); SCHED0();
  }

  // Epilogue: all cols < 2048 -> coeff uniformly -0.5*c^2.
  const int cq = lane >> 4;
  const int mrow = m0 + wm * 128;
#pragma unroll
  for (int f = 0; f < 8; ++f) {
#pragma unroll
    for (int r = 0; r < 4; ++r) {
      float contrib = 0.f;
#pragma unroll
      for (int g = 0; g < 4; ++g) {
        float vv = acc[f][g][r];
        contrib -= 0.5f * vv * vv;
      }
      contrib += __shfl_xor(contrib, 1);
      contrib += __shfl_xor(contrib, 2);
      contrib += __shfl_xor(contrib, 4);
      contrib += __shfl_xor(contrib, 8);
      if (lr == 0) atomicAdd(&arg[mrow + f * 16 + cq * 4 + r], contrib);
    }
  }
}

// --- finalize: sigmoid ------------------------------------------------------
__global__ __launch_bounds__(256) void k_fin(const float* __restrict__ arg,
                                             const float* __restrict__ b,
                                             float* __restrict__ out) {
  int i = blockIdx.x * 256 + threadIdx.x;
  float z = arg[i] + b[0];
  out[i] = 1.f / (1.f + __expf(-z));
}

extern "C" void kernel_launch(void* const* d_in, const int* in_sizes, int n_in,
                              void* d_out, int out_size, void* d_ws, size_t ws_size,
                              hipStream_t stream) {
  const float* x = (const float*)d_in[0];   // [16384, 2048]
  const float* w = (const float*)d_in[1];   // [2048]
  const float* b = (const float*)d_in[2];   // scalar
  const float* v = (const float*)d_in[3];   // [2048, 32, 64]
  float* out = (float*)d_out;               // [16384] fp32

  char* ws = (char*)d_ws;
  _Float16* xh  = (_Float16*)ws;                          // 67,108,864 B
  _Float16* vt  = (_Float16*)(ws + 67108864);             //  8,912,896 B
  float*    arg = (float*)(ws + 67108864 + 8912896);      //     65,536 B

  k_prep_v<<<2112, 256, 0, stream>>>(v, w, vt, arg);
  k_prep_xa<<<512, 256, 0, stream>>>(x, vt, xh, arg);
  k_gemm<<<512, 512, 0, stream>>>(xh, vt, arg);
  k_fin<<<64, 256, 0, stream>>>(arg, b, out);
}

// Round 11
// 354.952 us; speedup vs baseline: 1.4610x; 1.4610x over previous
//
#include <hip/hip_runtime.h>
#include <cstdint>
#include <cstddef>

// Problem constants
#define B_ROWS 16384
#define FEAT   2048
#define FIELD  32
#define KDIM   64
#define NCOLS  2048           // FIELD*KDIM (main quadratic columns)
#define NAUG   2176           // 2048 + 64 (vsum) + 1 (w) + 63 zero-pad

using half8   = __attribute__((ext_vector_type(8))) _Float16;
using half4   = __attribute__((ext_vector_type(4))) _Float16;
using floatx4 = __attribute__((ext_vector_type(4))) float;

// Async global->LDS, 16B per lane. LDS dest must be wave-uniform base + lane*16.
__device__ __forceinline__ void load_lds16(const void* g, void* l) {
  __builtin_amdgcn_global_load_lds((const __attribute__((address_space(1))) void*)g,
                                   (__attribute__((address_space(3))) void*)l, 16, 0, 0);
}

// --- prep A: v transpose + vsum + w/zero rows + arg zero (runs FIRST) ------
__global__ __launch_bounds__(256) void k_prep_v(const float* __restrict__ v,
                                                const float* __restrict__ w,
                                                _Float16* __restrict__ vt,
                                                float* __restrict__ arg) {
  const int bb = blockIdx.x;
  const int t = threadIdx.x;
  if (bb < 1024) {
    __shared__ _Float16 tile[64 * 68];
    const int f0 = (bb >> 5) * 64;
    const int n0 = (bb & 31) * 64;
#pragma unroll
    for (int j = 0; j < 4; ++j) {
      int c = j * 256 + t;
      int row = c >> 4;                           // f local
      int col = (c & 15) * 4;                     // n local
      float4 val = *(const float4*)(v + (size_t)(f0 + row) * NCOLS + n0 + col);
      tile[row * 68 + col + 0] = (_Float16)val.x;
      tile[row * 68 + col + 1] = (_Float16)val.y;
      tile[row * 68 + col + 2] = (_Float16)val.z;
      tile[row * 68 + col + 3] = (_Float16)val.w;
    }
    __syncthreads();
#pragma unroll
    for (int j = 0; j < 4; ++j) {
      int c = j * 256 + t;
      int nl = c >> 4;                            // n local (row of vt)
      int fl = (c & 15) * 4;                      // f local group of 4
      half4 h = { tile[(fl + 0) * 68 + nl], tile[(fl + 1) * 68 + nl],
                  tile[(fl + 2) * 68 + nl], tile[(fl + 3) * 68 + nl] };
      *(half4*)(vt + (size_t)(n0 + nl) * FEAT + f0 + fl) = h;
    }
  } else if (bb < 1536) {
    const int k = t & 63;
    const int f = (bb - 1024) * 4 + (t >> 6);
    float s = 0.f;
#pragma unroll
    for (int si = 0; si < FIELD; ++si) s += v[(size_t)f * NCOLS + si * KDIM + k];
    vt[(size_t)(NCOLS + k) * FEAT + f] = (_Float16)s;
  } else if (bb < 2048) {
    int idx = (bb - 1536) * 256 + t;              // 64*2048 elements
    int r = NCOLS + KDIM + (idx >> 11);           // 2112..2175
    int f = idx & 2047;
    vt[(size_t)r * FEAT + f] = (r == NCOLS + KDIM) ? (_Float16)w[f] : (_Float16)0.f;
  } else {
    arg[(bb - 2048) * 256 + t] = 0.f;
  }
}

// --- prep B: x fp32 -> xh fp16 FUSED with the aug thin-GEMM (R9-verified) --
__global__ __launch_bounds__(256) void k_prep_xa(const float* __restrict__ x,
                                                 const _Float16* __restrict__ vt,
                                                 _Float16* __restrict__ xh,
                                                 float* __restrict__ arg) {
  __shared__ __align__(16) _Float16 lds_a[32 * 64];
  __shared__ __align__(16) _Float16 lds_b[128 * 64];
  const int t = threadIdx.x;
  const int m0 = blockIdx.x * 32;
  const int lane = t & 63;
  const int wave = t >> 6;
  const int wm = (wave & 1) * 16;               // M offset (1 frag row)
  const int wn = (wave >> 1) * 64;              // N offset (4 frag cols)
  const int lr = lane & 15;
  const int lk = (lane >> 4) * 8;

  const int arow = t >> 3;
  const int akc  = t & 7;
  const float*    xsrc = x  + (size_t)(m0 + arow) * FEAT + akc * 8;
  _Float16*       xdst = xh + (size_t)(m0 + arow) * FEAT + akc * 8;
  _Float16*       adst = lds_a + arow * 64 + (akc ^ (arow & 7)) * 8;

  floatx4 acc[4] = {};

  for (int k0 = 0; k0 < FEAT; k0 += 64) {
    float4 va = *(const float4*)(xsrc + k0);
    float4 vb = *(const float4*)(xsrc + k0 + 4);
    half8 h = { (_Float16)va.x, (_Float16)va.y, (_Float16)va.z, (_Float16)va.w,
                (_Float16)vb.x, (_Float16)vb.y, (_Float16)vb.z, (_Float16)vb.w };
    *(half8*)(xdst + k0) = h;                   // xh for the main gemm
    *(half8*)adst = h;                          // swizzled LDS A-tile
#pragma unroll
    for (int i = 0; i < 4; ++i) {
      int c = i * 256 + t;                      // 0..1023
      int row = c >> 3;
      int g = (c & 7) ^ (row & 7);
      load_lds16(vt + (size_t)(NCOLS + row) * FEAT + k0 + g * 8, lds_b + c * 8);
    }
    __syncthreads();
#pragma unroll
    for (int ks = 0; ks < 64; ks += 32) {
      const int kc = (ks + lk) >> 3;
      const int ma = wm + lr;
      half8 af = *(const half8*)(lds_a + ma * 64 + (kc ^ (ma & 7)) * 8);
      half8 bf[4];
#pragma unroll
      for (int f = 0; f < 4; ++f) {
        int nb = wn + f * 16 + lr;
        bf[f] = *(const half8*)(lds_b + nb * 64 + (kc ^ (nb & 7)) * 8);
      }
#pragma unroll
      for (int fn = 0; fn < 4; ++fn)
        acc[fn] = __builtin_amdgcn_mfma_f32_16x16x32_f16(af, bf[fn],
                                                         acc[fn], 0, 0, 0);
    }
    __syncthreads();
  }

  const int cq = lane >> 4;
#pragma unroll
  for (int r = 0; r < 4; ++r) {
    float contrib = 0.f;
#pragma unroll
    for (int fn = 0; fn < 4; ++fn) {
      int col = wn + fn * 16 + lr;
      float vv = acc[fn][r];
      if (col < KDIM)            contrib += 0.5f * vv * vv;
      else if (col == KDIM)      contrib += vv;
    }
    contrib += __shfl_xor(contrib, 1);
    contrib += __shfl_xor(contrib, 2);
    contrib += __shfl_xor(contrib, 4);
    contrib += __shfl_xor(contrib, 8);
    if (lr == 0) atomicAdd(&arg[m0 + wm + cq * 4 + r], contrib);
  }
}

// --- main GEMM (cols 0..2047) + row-reduce epilogue ------------------------
// R11 = R8's verified segments/stage-schedule/vmcnt, with ONE barrier per
// phase and the lgkm drain moved AFTER the MFMA cluster.
//
// Why (R10 post-mortem): register prefetch (R10) spills -- acc=128 AGPR
// leaves only ~128 arch regs at the 2-wave/SIMD unified-file cap; 64 extra
// frag regs overflow (WRITE_SIZE 45MB scratch). The no-extra-register route
// to read/MFMA overlap is the COMPILER's counted lgkmcnt: hipcc emits
// fine-grained lgkmcnt(4/3/1/0) between ds_read and MFMA (m97 asm evidence)
// unless we force lgkmcnt(0)+sched_barrier before the cluster -- which
// R8's PHASE_TAIL did. Here each phase is:
//   { ds_reads; stage; PRIO(1); MFMA (compiler interleaves reads under it);
//     PRIO(0); LGKM0 (free now -- operands consumed; enforces WAR before
//     the barrier, rule #18); [VMCNT(4) at ph3 only]; BARRIER; SCHED0 }
// Hazard re-derivation (same segment map as R8):
//   RAW: reads of tile t guarded by vmcnt(4)+barrier at end-ph3(t-1)
//        (leaves only kg0(t+1) stages in flight; kg1(t) landed).  Tails:
//        t=30 drains vmcnt(0) (kg1(31) must land before ph2(31)); t=31 n/a.
//   WAR: ph2 stages sA0 after end-ph1's LGKM0+barrier (readers: ph0 lo,
//        ph1 hi); ph3 stages sB0 after end-ph0 (reader: ph0); ph0/ph1
//        stage buf^1-kg1 read last at ph2/ph3(t-1), drained end-ph3(t-1).
//   SCHED0 after each barrier stops next-phase ds_reads hoisting above it;
//   volatile LGKM0 (memory clobber) stops this phase's reads sinking below.
// Registers: identical to R8 (af[4]+bf[4]=32 frag regs) -> no spill.
// Grid: R8-verified 512 = 64m x 8n, zero tail, XCD swizzle 8*64 bijective,
// 2-n-group decode -> 2MB B L2-resident/XCD. Epilogue uniform -0.5c^2.
#define VMCNT(N) asm volatile("s_waitcnt vmcnt(" #N ")" ::: "memory")
#define LGKM0()  asm volatile("s_waitcnt lgkmcnt(0)" ::: "memory")
#define SCHED0() __builtin_amdgcn_sched_barrier(0)
#define BARRIER() __builtin_amdgcn_s_barrier()
#define PRIO(N) __builtin_amdgcn_s_setprio(N)

__global__ __launch_bounds__(512, 2) void k_gemm(const _Float16* __restrict__ xh,
                                                 const _Float16* __restrict__ vt,
                                                 float* __restrict__ arg) {
  __shared__ __align__(16) _Float16 lds[65536];   // 128 KiB
  const int tid  = threadIdx.x;
  const int lane = tid & 63;
  const int wave = tid >> 6;      // 0..7
  const int wm   = wave >> 2;     // 0..1 -> M offset wm*128
  const int wn   = wave & 3;      // 0..3 -> N offset wn*64
  const int lr   = lane & 15;     // frag row (A) / col (B)
  const int q    = lane >> 4;     // k-chunk within 32-k granule

  // R8 grid decode: XCD swizzle (512 = 8*64, bijective) + 2-n-group.
  const int bid = blockIdx.x;
  const int wg  = (bid & 7) * 64 + (bid >> 3);
  const int ng  = wg >> 7;
  const int rem = wg & 127;
  const int mi  = rem >> 1;
  const int nr  = rem & 1;
  const int m0  = mi * 256;
  const int n0  = (ng * 2 + nr) * 256;           // 0..1792

  // fragment LDS offsets (halves) within any granule segment.
  int offA[4], offB[4];
#pragma unroll
  for (int f = 0; f < 4; ++f) {
    int L = f * 16 + lr;
    int u = wm * 4 + q;
    offA[f] = L * 64 + ((u ^ (L & 7)) * 8);
  }
#pragma unroll
  for (int g = 0; g < 4; ++g) {
    int L = (wn & 1) * 64 + g * 16 + lr;
    int u = (wn >> 1) * 4 + q;
    offB[g] = L * 64 + ((u ^ (L & 7)) * 8);
  }

  // staging source decode: linear chunk tid -> (row, kc); dest+4096 -> row+64.
  const int L0   = tid >> 3;
  const int u0   = (tid & 7) ^ (L0 & 7);
  const int row0 = (u0 >> 2) * 128 + L0;
  const int kc0  = u0 & 3;
  const _Float16* pA0 = xh + (size_t)(m0 + row0) * FEAT + kc0 * 8;
  const _Float16* pA1 = pA0 + (size_t)64 * FEAT;
  const _Float16* pB0 = vt + (size_t)(n0 + row0) * FEAT + kc0 * 8;  // rows < 2048
  const _Float16* pB1 = pB0 + (size_t)64 * FEAT;

  auto stageA = [&](int koff, int seg) {
    load_lds16(pA0 + koff, lds + seg + tid * 8);
    load_lds16(pA1 + koff, lds + seg + 4096 + tid * 8);
  };
  auto stageB = [&](int koff, int seg) {
    load_lds16(pB0 + koff, lds + seg + tid * 8);
    load_lds16(pB1 + koff, lds + seg + 4096 + tid * 8);
  };

  floatx4 acc[8][4] = {};
  half8 af[4], bf[4];

  // prologue: K-tile 0 (both granules) + K-tile 1 kg0 (12 loads).
  stageA(0, 0);       stageB(0, 32768);
  stageA(32, 8192);   stageB(32, 40960);
  stageA(64, 16384);  stageB(64, 49152);
  VMCNT(4);                      // K-tile 0 fully landed (kg0(1) in flight)
  BARRIER();
  SCHED0();

#pragma unroll 2
  for (int t = 0; t < 32; ++t) {
    const int sA0  = ((t & 1) << 1) * 8192;                 // segA(buf, kg0)
    const int sB0  = 32768 + sA0;                           // segB(buf, kg0)
    const int sPA1 = ((((t + 1) & 1) << 1) | 1) * 8192;     // segA(buf^1, kg1)

    // ---- phase 0: ks=0, M-frags 0-3; stage A kg1(t+1) ---------------------
#pragma unroll
    for (int g = 0; g < 4; ++g) bf[g] = *(const half8*)(lds + sB0 + offB[g]);
#pragma unroll
    for (int f = 0; f < 4; ++f) af[f] = *(const half8*)(lds + sA0 + offA[f]);
    if (t < 31) stageA((t + 1) * 64 + 32, sPA1);
    PRIO(1);
#pragma unroll
    for (int f = 0; f < 4; ++f)
#pragma unroll
      for (int g = 0; g < 4; ++g)
        acc[f][g] = __builtin_amdgcn_mfma_f32_16x16x32_f16(af[f], bf[g],
                                                           acc[f][g], 0, 0, 0);
    PRIO(0);
    LGKM0();
    BARRIER(); SCHED0();

    // ---- phase 1: ks=0, M-frags 4-7 (bf reused); stage B kg1(t+1) ---------
#pragma unroll
    for (int f = 0; f < 4; ++f) af[f] = *(const half8*)(lds + sA0 + 4096 + offA[f]);
    if (t < 31) stageB((t + 1) * 64 + 32, 32768 + sPA1);
    PRIO(1);
#pragma unroll
    for (int f = 0; f < 4; ++f)
#pragma unroll
      for (int g = 0; g < 4; ++g)
        acc[4 + f][g] = __builtin_amdgcn_mfma_f32_16x16x32_f16(af[f], bf[g],
                                                               acc[4 + f][g], 0, 0, 0);
    PRIO(0);
    LGKM0();
    BARRIER(); SCHED0();

    // ---- phase 2: ks=32, M-frags 0-3; stage A kg0(t+2) --------------------
#pragma unroll
    for (int g = 0; g < 4; ++g) bf[g] = *(const half8*)(lds + sB0 + 8192 + offB[g]);
#pragma unroll
    for (int f = 0; f < 4; ++f) af[f] = *(const half8*)(lds + sA0 + 8192 + offA[f]);
    if (t < 30) stageA((t + 2) * 64, sA0);
    PRIO(1);
#pragma unroll
    for (int f = 0; f < 4; ++f)
#pragma unroll
      for (int g = 0; g < 4; ++g)
        acc[f][g] = __builtin_amdgcn_mfma_f32_16x16x32_f16(af[f], bf[g],
                                                           acc[f][g], 0, 0, 0);
    PRIO(0);
    LGKM0();
    BARRIER(); SCHED0();

    // ---- phase 3: ks=32, M-frags 4-7; stage B kg0(t+2); counted vmcnt -----
#pragma unroll
    for (int f = 0; f < 4; ++f) af[f] = *(const half8*)(lds + sA0 + 12288 + offA[f]);
    if (t < 30) stageB((t + 2) * 64, sB0);
    PRIO(1);
#pragma unroll
    for (int f = 0; f < 4; ++f)
#pragma unroll
      for (int g = 0; g < 4; ++g)
        acc[4 + f][g] = __builtin_amdgcn_mfma_f32_16x16x32_f16(af[f], bf[g],
                                                               acc[4 + f][g], 0, 0, 0);
    PRIO(0);
    LGKM0();
    // steady state: only kg0(t+2)'s 4 loads stay in flight across the
    // boundary (kg1(t+1) landed). t=30: no t+2 stages -> drain so kg1(31)
    // lands before ph2(31) reads it. t=31: nothing outstanding.
    if (t < 30) { VMCNT(4); } else { VMCNT(0); }
    BARRIER(); SCHED0();
  }

  // Epilogue: all cols < 2048 -> coeff uniformly -0.5*c^2.
  const int cq = lane >> 4;
  const int mrow = m0 + wm * 128;
#pragma unroll
  for (int f = 0; f < 8; ++f) {
#pragma unroll
    for (int r = 0; r < 4; ++r) {
      float contrib = 0.f;
#pragma unroll
      for (int g = 0; g < 4; ++g) {
        float vv = acc[f][g][r];
        contrib -= 0.5f * vv * vv;
      }
      contrib += __shfl_xor(contrib, 1);
      contrib += __shfl_xor(contrib, 2);
      contrib += __shfl_xor(contrib, 4);
      contrib += __shfl_xor(contrib, 8);
      if (lr == 0) atomicAdd(&arg[mrow + f * 16 + cq * 4 + r], contrib);
    }
  }
}

// --- finalize: sigmoid ------------------------------------------------------
__global__ __launch_bounds__(256) void k_fin(const float* __restrict__ arg,
                                             const float* __restrict__ b,
                                             float* __restrict__ out) {
  int i = blockIdx.x * 256 + threadIdx.x;
  float z = arg[i] + b[0];
  out[i] = 1.f / (1.f + __expf(-z));
}

extern "C" void kernel_launch(void* const* d_in, const int* in_sizes, int n_in,
                              void* d_out, int out_size, void* d_ws, size_t ws_size,
                              hipStream_t stream) {
  const float* x = (const float*)d_in[0];   // [16384, 2048]
  const float* w = (const float*)d_in[1];   // [2048]
  const float* b = (const float*)d_in[2];   // scalar
  const float* v = (const float*)d_in[3];   // [2048, 32, 64]
  float* out = (float*)d_out;               // [16384] fp32

  char* ws = (char*)d_ws;
  _Float16* xh  = (_Float16*)ws;                          // 67,108,864 B
  _Float16* vt  = (_Float16*)(ws + 67108864);             //  8,912,896 B
  float*    arg = (float*)(ws + 67108864 + 8912896);      //     65,536 B

  k_prep_v<<<2112, 256, 0, stream>>>(v, w, vt, arg);
  k_prep_xa<<<512, 256, 0, stream>>>(x, vt, xh, arg);
  k_gemm<<<512, 512, 0, stream>>>(xh, vt, arg);
  k_fin<<<64, 256, 0, stream>>>(arg, b, out);
}